// Round 11
// baseline (239.663 us; speedup 1.0000x reference)
//
#include <hip/hip_runtime.h>
#include <hip/hip_bf16.h>
#include <stdint.h>

constexpr int N_NODES = 50000;
constexpr int N_EDGES = 1600000;
constexpr int IN_DIM  = 500;
constexpr int KPAD    = 512;   // zero-padded K: 16 MFMA steps of 32
constexpr int HID     = 64;
constexpr int OUTC    = 68;    // 64 h2 cols + 4 composed projection cols
constexpr int NCPAD   = 80;    // padded cols: 5 fragments x 16
constexpr int NFRAG   = 5;
constexpr int KSTEPS  = 16;

constexpr int BNODES  = 128;   // nodes per bucket (391 buckets -> k_fine fills the GPU)
constexpr int NBUCK   = (N_NODES + BNODES - 1) / BNODES;  // 391
constexpr int EPB     = 2048;  // edges per block (hist/partition) -> 782 blocks
constexpr int NEBLK   = (N_EDGES + EPB - 1) / EPB;        // 782

#define DEVI __device__ __forceinline__

typedef __attribute__((ext_vector_type(8))) short bf16x8;
typedef __attribute__((ext_vector_type(4))) float f32x4;

DEVI float wred64(float v) {
#pragma unroll
    for (int m = 32; m; m >>= 1) v += __shfl_xor(v, m, 64);
    return v;
}

DEVI float bf_hi(uint32_t u) { return __uint_as_float(u & 0xffff0000u); }
DEVI float bf_lo(uint32_t u) { return __uint_as_float(u << 16); }

DEVI uint16_t f2bf(float f) {
    union { __hip_bfloat16 h; uint16_t u; } c;
    c.h = __float2bfloat16(f);
    return c.u;
}

// ---------------- CSR build: bucketed counting sort ----------------
// bucket = dst >> 7  (BNODES = 128)
__global__ __launch_bounds__(256) void k_bhist(const int* __restrict__ dst,
                                               int* __restrict__ bcnt) {
    __shared__ int h[NBUCK];
    int t = threadIdx.x;
    for (int i = t; i < NBUCK; i += 256) h[i] = 0;
    __syncthreads();
    int blockBase = blockIdx.x * EPB;
#pragma unroll
    for (int j = 0; j < 2; ++j) {
        int e = blockBase + j * 1024 + t * 4;
        if (e + 3 < N_EDGES) {
            int4 d4 = *(const int4*)(dst + e);
            atomicAdd(&h[d4.x >> 7], 1);
            atomicAdd(&h[d4.y >> 7], 1);
            atomicAdd(&h[d4.z >> 7], 1);
            atomicAdd(&h[d4.w >> 7], 1);
        }
    }
    __syncthreads();
    for (int i = t; i < NBUCK; i += 256)
        if (h[i]) atomicAdd(&bcnt[i], h[i]);
}

__global__ __launch_bounds__(512) void k_bscan(const int* __restrict__ bcnt,
                                               int* __restrict__ bbase,
                                               int* __restrict__ bcur) {
    __shared__ int s[512];
    int t = threadIdx.x;
    int v = (t < NBUCK) ? bcnt[t] : 0;
    s[t] = v;
    __syncthreads();
    for (int d = 1; d < 512; d <<= 1) {
        int w = (t >= d) ? s[t - d] : 0;
        __syncthreads();
        s[t] += w;
        __syncthreads();
    }
    if (t < NBUCK) {
        bbase[t] = s[t] - v;
        bcur[t]  = s[t] - v;
    }
    if (t == NBUCK - 1) bbase[NBUCK] = s[t];
}

__global__ __launch_bounds__(256) void k_part(const int* __restrict__ src,
                                              const int* __restrict__ dst,
                                              int* __restrict__ bcur,
                                              uint32_t* __restrict__ ebuf) {
    __shared__ int h[NBUCK];
    __shared__ int gb[NBUCK];
    int t = threadIdx.x;
    for (int i = t; i < NBUCK; i += 256) h[i] = 0;
    __syncthreads();
    uint32_t pk[8];
    int blockBase = blockIdx.x * EPB;
#pragma unroll
    for (int j = 0; j < 2; ++j) {
        int e = blockBase + j * 1024 + t * 4;
        if (e + 3 < N_EDGES) {
            int4 s4 = *(const int4*)(src + e);
            int4 d4 = *(const int4*)(dst + e);
            pk[4 * j + 0] = ((uint32_t)d4.x << 16) | (uint32_t)s4.x;
            pk[4 * j + 1] = ((uint32_t)d4.y << 16) | (uint32_t)s4.y;
            pk[4 * j + 2] = ((uint32_t)d4.z << 16) | (uint32_t)s4.z;
            pk[4 * j + 3] = ((uint32_t)d4.w << 16) | (uint32_t)s4.w;
        } else {
            pk[4 * j + 0] = 0xffffffffu;
            pk[4 * j + 1] = 0xffffffffu;
            pk[4 * j + 2] = 0xffffffffu;
            pk[4 * j + 3] = 0xffffffffu;
        }
    }
#pragma unroll
    for (int j = 0; j < 8; ++j) {
        uint32_t b = pk[j] >> 23;   // dst >> 7
        if (b < NBUCK) atomicAdd(&h[b], 1);
    }
    __syncthreads();
    for (int i = t; i < NBUCK; i += 256)
        gb[i] = h[i] ? atomicAdd(&bcur[i], h[i]) : 0;
    __syncthreads();
#pragma unroll
    for (int j = 0; j < 8; ++j) {
        uint32_t b = pk[j] >> 23;
        if (b < NBUCK) {
            int pos = atomicAdd(&gb[b], 1);
            ebuf[pos] = pk[j];
        }
    }
}

__global__ __launch_bounds__(256) void k_fine(const int* __restrict__ bbase,
                                              const uint32_t* __restrict__ ebuf,
                                              int* __restrict__ rowptr,
                                              float* __restrict__ dinv,
                                              uint16_t* __restrict__ csr16) {
    __shared__ int lcnt[BNODES];
    __shared__ int lcur[BNODES];
    int b = blockIdx.x, t = threadIdx.x;
    int ebase = bbase[b], eend = bbase[b + 1];
    int ecnt = eend - ebase;
    if (t < BNODES) lcnt[t] = 0;
    __syncthreads();
    for (int i = t; i < ecnt; i += 256)
        atomicAdd(&lcnt[(ebuf[ebase + i] >> 16) & (BNODES - 1)], 1);
    __syncthreads();
    int myc = (t < BNODES) ? lcnt[t] : 0;
    if (t < BNODES) lcur[t] = myc;
    __syncthreads();
    for (int d = 1; d < BNODES; d <<= 1) {
        int w = (t >= d && t < BNODES) ? lcur[t - d] : 0;
        __syncthreads();
        if (t < BNODES) lcur[t] += w;
        __syncthreads();
    }
    if (t < BNODES) {
        int excl = lcur[t] - myc;
        int node = b * BNODES + t;
        if (node < N_NODES) {
            rowptr[node] = ebase + excl;
            dinv[node] = rsqrtf((float)(myc > 1 ? myc : 1));
        }
        lcur[t] = ebase + excl;
    }
    if (b == NBUCK - 1 && t == 0) rowptr[N_NODES] = eend;
    __syncthreads();
    for (int i = t; i < ecnt; i += 256) {
        uint32_t pk = ebuf[ebase + i];
        int pos = atomicAdd(&lcur[(pk >> 16) & (BNODES - 1)], 1);
        csr16[pos] = (uint16_t)(pk & 0xffffu);
    }
}

// ---- weight prep: composed weights -> bf16 in MFMA-B fragment order ----
__global__ void k_prep(const float* __restrict__ Wl, const float* __restrict__ bl,
                       const float* __restrict__ glw, const float* __restrict__ glb,
                       const float* __restrict__ W1,
                       uint16_t* __restrict__ Wfrag, float* __restrict__ consts) {
    int idx = blockIdx.x * 256 + threadIdx.x;
    if (idx < KPAD * NCPAD) {
        int k = idx / NCPAD, c = idx - k * NCPAD;
        float v = 0.f;
        if (k < IN_DIM && c < OUTC) {
            if (c < HID) {
                v = W1[k * HID + c];
            } else {
                int pp = c - HID, g = pp >> 1, half = pp & 1;
                const float* wv = glw + g * 128 + half * 64;
                float s = 0.f;
                for (int j = 0; j < 64; ++j) s += Wl[k * 64 + j] * wv[j];
                v = s;
            }
        }
        int s  = k >> 5;
        int kk = k & 31;
        int g  = kk >> 3;
        int i  = kk & 7;
        int f  = c >> 4;
        int cl = c & 15;
        int lane = g * 16 + cl;
        Wfrag[(((size_t)s * NFRAG + f) * 64 + lane) * 8 + i] = f2bf(v);
    }
    if (idx < 4) {
        int g = idx >> 1, half = idx & 1;
        const float* wv = glw + g * 128 + half * 64;
        float s = 0.f;
        for (int j = 0; j < 64; ++j) s += bl[j] * wv[j];
        if (half) s += glb[g];
        consts[idx] = s;
    }
}

// ---------------- fused front GEMM via MFMA bf16, 2-deep load pipeline ----------------
__global__ __launch_bounds__(256)
void k_gemm_front(const float* __restrict__ x, const uint16_t* __restrict__ Wfrag,
                  const float* __restrict__ consts, const float* __restrict__ b1,
                  const float* __restrict__ dinv,
                  float* __restrict__ h2f, uint16_t* __restrict__ h2b,
                  float4* __restrict__ projd, float4* __restrict__ projs) {
    __shared__ float shp[64][4];
    int tid  = threadIdx.x;
    int wv   = tid >> 6;
    int lane = tid & 63;
    int rbase = blockIdx.x * 64 + wv * 16;
    int row   = rbase + (lane & 15);
    bool rowok = row < N_NODES;
    const float* xr = x + (size_t)row * IN_DIM;
    int koff = (lane >> 4) * 8;

    const bf16x8* wfv = (const bf16x8*)Wfrag;

    f32x4 acc[NFRAG];
#pragma unroll
    for (int f = 0; f < NFRAG; ++f) acc[f] = (f32x4){0.f, 0.f, 0.f, 0.f};

    auto LD4 = [&](int gk) -> float4 {
        float4 v = make_float4(0.f, 0.f, 0.f, 0.f);
        if (rowok) {
            if (gk + 3 < IN_DIM) {
                v = *(const float4*)(xr + gk);
            } else {
                if (gk + 0 < IN_DIM) v.x = xr[gk + 0];
                if (gk + 1 < IN_DIM) v.y = xr[gk + 1];
                if (gk + 2 < IN_DIM) v.z = xr[gk + 2];
                if (gk + 3 < IN_DIM) v.w = xr[gk + 3];
            }
        }
        return v;
    };

    float4 pbuf[3][2];   // 2-deep prefetch ring; fully unrolled loop -> constant indices
    pbuf[0][0] = LD4(koff);      pbuf[0][1] = LD4(koff + 4);
    pbuf[1][0] = LD4(32 + koff); pbuf[1][1] = LD4(32 + koff + 4);
#pragma unroll
    for (int s = 0; s < KSTEPS; ++s) {
        if (s + 2 < KSTEPS) {
            int gk = (s + 2) * 32 + koff;
            pbuf[(s + 2) % 3][0] = LD4(gk);
            pbuf[(s + 2) % 3][1] = LD4(gk + 4);
        }
        float4 c0 = pbuf[s % 3][0], c1 = pbuf[s % 3][1];
        bf16x8 af;
        af[0] = (short)f2bf(c0.x); af[1] = (short)f2bf(c0.y);
        af[2] = (short)f2bf(c0.z); af[3] = (short)f2bf(c0.w);
        af[4] = (short)f2bf(c1.x); af[5] = (short)f2bf(c1.y);
        af[6] = (short)f2bf(c1.z); af[7] = (short)f2bf(c1.w);
        const bf16x8* wrow = wfv + (size_t)s * NFRAG * 64 + lane;
#pragma unroll
        for (int f = 0; f < NFRAG; ++f) {
            bf16x8 bf = wrow[f * 64];
            acc[f] = __builtin_amdgcn_mfma_f32_16x16x32_bf16(af, bf, acc[f], 0, 0, 0);
        }
    }

    int cl  = lane & 15;
    int rg2 = lane >> 4;
#pragma unroll
    for (int f = 0; f < 4; ++f) {
        int c = f * 16 + cl;
        float bc = b1[c];
#pragma unroll
        for (int r = 0; r < 4; ++r) {
            int grow = rbase + rg2 * 4 + r;
            if (grow < N_NODES) {
                float hv = fmaxf(acc[f][r] + bc, 0.f);
                h2f[(size_t)grow * HID + c] = hv;
                h2b[(size_t)grow * HID + c] = f2bf(hv);
            }
        }
    }
    if (cl < 4) {
#pragma unroll
        for (int r = 0; r < 4; ++r) {
            int rl = wv * 16 + rg2 * 4 + r;
            shp[rl][cl] = acc[4][r] + consts[cl];
        }
    }
    __syncthreads();
    if (tid < 64) {
        int grow = blockIdx.x * 64 + tid;
        if (grow < N_NODES) {
            float dv = dinv[grow];
            projd[grow] = make_float4(shp[tid][0], shp[tid][2], dv, 0.f);
            projs[grow] = make_float4(shp[tid][1], shp[tid][3], dv, 0.f);
        }
    }
}

// ---------------- hop 0: on-the-fly factors, bf16 gather, 8x-unrolled broadcast loop ----
__global__ __launch_bounds__(256)
void k_hop0(const int* __restrict__ rowptr, const uint16_t* __restrict__ csr16,
            const float4* __restrict__ projd, const float4* __restrict__ projs,
            const uint16_t* __restrict__ h2b, const float* __restrict__ h2f,
            const float* __restrict__ faw, const float* __restrict__ fab,
            uint32_t* __restrict__ fc, float4* __restrict__ p1d, float4* __restrict__ p1s) {
    int wave = __builtin_amdgcn_readfirstlane(threadIdx.x >> 6);
    int lane = threadIdx.x & 63;
    int v = blockIdx.x * 4 + wave;
    int s = __builtin_amdgcn_readfirstlane(rowptr[v]);
    int e = __builtin_amdgcn_readfirstlane(rowptr[v + 1]);
    float4 pv = projd[v];
    float pd0 = pv.x, pd1 = pv.y, dv = pv.z;
    float acc0 = 0.f, acc1 = 0.f;
    for (int b2 = s; b2 < e; b2 += 64) {
        int pos = b2 + lane;
        bool val = pos < e;
        int uj = val ? (int)csr16[pos] : 0;
        float4 su = val ? projs[uj] : make_float4(0.f, 0.f, 0.f, 0.f);
        float dd = dv * su.z;
        int pkl = (int)((uint32_t)f2bf(tanhf(pd0 + su.x) * dd)
                      | ((uint32_t)f2bf(tanhf(pd1 + su.y) * dd) << 16));
        int cnt = min(64, e - b2);
        int j = 0;
        for (; j + 8 <= cnt; j += 8) {
            int u0 = __shfl(uj, j + 0, 64); uint32_t k0 = (uint32_t)__shfl(pkl, j + 0, 64);
            int u1 = __shfl(uj, j + 1, 64); uint32_t k1 = (uint32_t)__shfl(pkl, j + 1, 64);
            int u2 = __shfl(uj, j + 2, 64); uint32_t k2 = (uint32_t)__shfl(pkl, j + 2, 64);
            int u3 = __shfl(uj, j + 3, 64); uint32_t k3 = (uint32_t)__shfl(pkl, j + 3, 64);
            int u4 = __shfl(uj, j + 4, 64); uint32_t k4 = (uint32_t)__shfl(pkl, j + 4, 64);
            int u5 = __shfl(uj, j + 5, 64); uint32_t k5 = (uint32_t)__shfl(pkl, j + 5, 64);
            int u6 = __shfl(uj, j + 6, 64); uint32_t k6 = (uint32_t)__shfl(pkl, j + 6, 64);
            int u7 = __shfl(uj, j + 7, 64); uint32_t k7 = (uint32_t)__shfl(pkl, j + 7, 64);
            uint32_t h0 = h2b[(size_t)u0 * 64 + lane];
            uint32_t h1 = h2b[(size_t)u1 * 64 + lane];
            uint32_t h2 = h2b[(size_t)u2 * 64 + lane];
            uint32_t h3 = h2b[(size_t)u3 * 64 + lane];
            uint32_t h4 = h2b[(size_t)u4 * 64 + lane];
            uint32_t h5 = h2b[(size_t)u5 * 64 + lane];
            uint32_t h6 = h2b[(size_t)u6 * 64 + lane];
            uint32_t h7 = h2b[(size_t)u7 * 64 + lane];
            float f0 = bf_lo(h0), f1 = bf_lo(h1), f2 = bf_lo(h2), f3 = bf_lo(h3);
            float f4 = bf_lo(h4), f5 = bf_lo(h5), f6 = bf_lo(h6), f7 = bf_lo(h7);
            acc0 = fmaf(bf_lo(k0), f0, acc0); acc1 = fmaf(bf_hi(k0), f0, acc1);
            acc0 = fmaf(bf_lo(k1), f1, acc0); acc1 = fmaf(bf_hi(k1), f1, acc1);
            acc0 = fmaf(bf_lo(k2), f2, acc0); acc1 = fmaf(bf_hi(k2), f2, acc1);
            acc0 = fmaf(bf_lo(k3), f3, acc0); acc1 = fmaf(bf_hi(k3), f3, acc1);
            acc0 = fmaf(bf_lo(k4), f4, acc0); acc1 = fmaf(bf_hi(k4), f4, acc1);
            acc0 = fmaf(bf_lo(k5), f5, acc0); acc1 = fmaf(bf_hi(k5), f5, acc1);
            acc0 = fmaf(bf_lo(k6), f6, acc0); acc1 = fmaf(bf_hi(k6), f6, acc1);
            acc0 = fmaf(bf_lo(k7), f7, acc0); acc1 = fmaf(bf_hi(k7), f7, acc1);
        }
        for (; j < cnt; ++j) {
            int u = __shfl(uj, j, 64);
            uint32_t pk = (uint32_t)__shfl(pkl, j, 64);
            float hv = bf_lo((uint32_t)h2b[(size_t)u * 64 + lane]);
            acc0 = fmaf(bf_lo(pk), hv, acc0);
            acc1 = fmaf(bf_hi(pk), hv, acc1);
        }
    }
    float h2v = h2f[(size_t)v * 64 + lane];
    float f0 = fmaf(0.7f, acc0, 0.3f * h2v);
    float f1 = fmaf(0.7f, acc1, 0.3f * h2v);
    fc[(size_t)v * 64 + lane] = (uint32_t)f2bf(f0) | ((uint32_t)f2bf(f1) << 16);
    float wpd0 = faw[1 * 128 + lane];
    float wps0 = faw[1 * 128 + 64 + lane];
    float wpd1 = faw[3 * 128 + lane];
    float wps1 = faw[3 * 128 + 64 + lane];
    float r0 = wred64(f0 * wpd0);
    float r1 = wred64(f0 * wps0);
    float r2 = wred64(f1 * wpd1);
    float r3 = wred64(f1 * wps1);
    if (lane == 0) {
        p1d[v] = make_float4(r0, r2, dv, 0.f);
        p1s[v] = make_float4(r1 + fab[1], r3 + fab[3], dv, 0.f);
    }
}

// ---------------- hop 1 + final output GEMM [128]->7, 8x-unrolled ----
__global__ __launch_bounds__(256)
void k_hop1(const int* __restrict__ rowptr, const uint16_t* __restrict__ csr16,
            const float4* __restrict__ p1d, const float4* __restrict__ p1s,
            const uint32_t* __restrict__ fc, const float* __restrict__ h2f,
            const float* __restrict__ W2, const float* __restrict__ b2,
            float* __restrict__ out) {
    int wave = __builtin_amdgcn_readfirstlane(threadIdx.x >> 6);
    int lane = threadIdx.x & 63;
    int v = blockIdx.x * 4 + wave;
    int s = __builtin_amdgcn_readfirstlane(rowptr[v]);
    int e = __builtin_amdgcn_readfirstlane(rowptr[v + 1]);
    float4 pv = p1d[v];
    float pd0 = pv.x, pd1 = pv.y, dv = pv.z;
    float acc0 = 0.f, acc1 = 0.f;
    for (int b2 = s; b2 < e; b2 += 64) {
        int pos = b2 + lane;
        bool val = pos < e;
        int uj = val ? (int)csr16[pos] : 0;
        float4 su = val ? p1s[uj] : make_float4(0.f, 0.f, 0.f, 0.f);
        float dd = dv * su.z;
        int pkl = (int)((uint32_t)f2bf(tanhf(pd0 + su.x) * dd)
                      | ((uint32_t)f2bf(tanhf(pd1 + su.y) * dd) << 16));
        int cnt = min(64, e - b2);
        int j = 0;
        for (; j + 8 <= cnt; j += 8) {
            int u0 = __shfl(uj, j + 0, 64); uint32_t k0 = (uint32_t)__shfl(pkl, j + 0, 64);
            int u1 = __shfl(uj, j + 1, 64); uint32_t k1 = (uint32_t)__shfl(pkl, j + 1, 64);
            int u2 = __shfl(uj, j + 2, 64); uint32_t k2 = (uint32_t)__shfl(pkl, j + 2, 64);
            int u3 = __shfl(uj, j + 3, 64); uint32_t k3 = (uint32_t)__shfl(pkl, j + 3, 64);
            int u4 = __shfl(uj, j + 4, 64); uint32_t k4 = (uint32_t)__shfl(pkl, j + 4, 64);
            int u5 = __shfl(uj, j + 5, 64); uint32_t k5 = (uint32_t)__shfl(pkl, j + 5, 64);
            int u6 = __shfl(uj, j + 6, 64); uint32_t k6 = (uint32_t)__shfl(pkl, j + 6, 64);
            int u7 = __shfl(uj, j + 7, 64); uint32_t k7 = (uint32_t)__shfl(pkl, j + 7, 64);
            uint32_t g0 = fc[(size_t)u0 * 64 + lane];
            uint32_t g1 = fc[(size_t)u1 * 64 + lane];
            uint32_t g2 = fc[(size_t)u2 * 64 + lane];
            uint32_t g3 = fc[(size_t)u3 * 64 + lane];
            uint32_t g4 = fc[(size_t)u4 * 64 + lane];
            uint32_t g5 = fc[(size_t)u5 * 64 + lane];
            uint32_t g6 = fc[(size_t)u6 * 64 + lane];
            uint32_t g7 = fc[(size_t)u7 * 64 + lane];
            acc0 = fmaf(bf_lo(k0), bf_lo(g0), acc0); acc1 = fmaf(bf_hi(k0), bf_hi(g0), acc1);
            acc0 = fmaf(bf_lo(k1), bf_lo(g1), acc0); acc1 = fmaf(bf_hi(k1), bf_hi(g1), acc1);
            acc0 = fmaf(bf_lo(k2), bf_lo(g2), acc0); acc1 = fmaf(bf_hi(k2), bf_hi(g2), acc1);
            acc0 = fmaf(bf_lo(k3), bf_lo(g3), acc0); acc1 = fmaf(bf_hi(k3), bf_hi(g3), acc1);
            acc0 = fmaf(bf_lo(k4), bf_lo(g4), acc0); acc1 = fmaf(bf_hi(k4), bf_hi(g4), acc1);
            acc0 = fmaf(bf_lo(k5), bf_lo(g5), acc0); acc1 = fmaf(bf_hi(k5), bf_hi(g5), acc1);
            acc0 = fmaf(bf_lo(k6), bf_lo(g6), acc0); acc1 = fmaf(bf_hi(k6), bf_hi(g6), acc1);
            acc0 = fmaf(bf_lo(k7), bf_lo(g7), acc0); acc1 = fmaf(bf_hi(k7), bf_hi(g7), acc1);
        }
        for (; j < cnt; ++j) {
            int u = __shfl(uj, j, 64);
            uint32_t pk = (uint32_t)__shfl(pkl, j, 64);
            uint32_t g = fc[(size_t)u * 64 + lane];
            acc0 = fmaf(bf_lo(pk), bf_lo(g), acc0);
            acc1 = fmaf(bf_hi(pk), bf_hi(g), acc1);
        }
    }
    float h2v = h2f[(size_t)v * 64 + lane];
    float f0 = fmaf(0.7f, acc0, 0.3f * h2v);
    float f1 = fmaf(0.7f, acc1, 0.3f * h2v);
#pragma unroll
    for (int o = 0; o < 7; ++o) {
        float contrib = f0 * W2[lane * 7 + o] + f1 * W2[(64 + lane) * 7 + o];
        float sum = wred64(contrib);
        if (lane == 0) out[v * 7 + o] = sum + b2[o];
    }
}

extern "C" void kernel_launch(void* const* d_in, const int* in_sizes, int n_in,
                              void* d_out, int out_size, void* d_ws, size_t ws_size,
                              hipStream_t stream) {
    const float* x   = (const float*)d_in[0];
    const int*   src = (const int*)d_in[1];
    const int*   dst = (const int*)d_in[2];
    const float* Wl  = (const float*)d_in[3];
    const float* bl  = (const float*)d_in[4];
    const float* glw = (const float*)d_in[5];
    const float* glb = (const float*)d_in[6];
    const float* W1  = (const float*)d_in[7];
    const float* b1  = (const float*)d_in[8];
    const float* faw = (const float*)d_in[9];
    const float* fab = (const float*)d_in[10];
    const float* W2  = (const float*)d_in[11];
    const float* b2  = (const float*)d_in[12];
    float* out = (float*)d_out;

    uint8_t* p = (uint8_t*)d_ws;
    auto carve = [&](size_t bytes) {
        uint8_t* q = p;
        p += (bytes + 255) & ~(size_t)255;
        return q;
    };
    uint16_t* Wfrag   = (uint16_t*)carve((size_t)KPAD * NCPAD * 2);
    float*    consts  = (float*)carve(16);
    int*      bcnt    = (int*)carve(NBUCK * 4);
    int*      bbase   = (int*)carve((NBUCK + 1) * 4);
    int*      bcur    = (int*)carve(NBUCK * 4);
    int*      rowptr  = (int*)carve((N_NODES + 1) * 4);
    float*    dinv    = (float*)carve(N_NODES * 4);
    uint32_t* ebuf    = (uint32_t*)carve((size_t)N_EDGES * 4);
    uint16_t* csr16   = (uint16_t*)carve((size_t)N_EDGES * 2);
    float*    h2f     = (float*)carve((size_t)N_NODES * 64 * 4);
    uint16_t* h2b     = (uint16_t*)carve((size_t)N_NODES * 64 * 2);
    float4*   projd   = (float4*)carve((size_t)N_NODES * 16);
    float4*   projs   = (float4*)carve((size_t)N_NODES * 16);
    uint32_t* fc      = (uint32_t*)carve((size_t)N_NODES * 64 * 4);
    float4*   p1d     = (float4*)carve((size_t)N_NODES * 16);
    float4*   p1s     = (float4*)carve((size_t)N_NODES * 16);

    hipMemsetAsync(bcnt, 0, NBUCK * 4, stream);
    k_bhist<<<NEBLK, 256, 0, stream>>>(dst, bcnt);
    k_bscan<<<1, 512, 0, stream>>>(bcnt, bbase, bcur);
    k_part<<<NEBLK, 256, 0, stream>>>(src, dst, bcur, ebuf);
    k_fine<<<NBUCK, 256, 0, stream>>>(bbase, ebuf, rowptr, dinv, csr16);
    k_prep<<<(KPAD * NCPAD + 255) / 256, 256, 0, stream>>>(Wl, bl, glw, glb, W1, Wfrag, consts);
    k_gemm_front<<<(N_NODES + 63) / 64, 256, 0, stream>>>(x, Wfrag, consts, b1, dinv,
                                                          h2f, h2b, projd, projs);
    k_hop0<<<N_NODES / 4, 256, 0, stream>>>(rowptr, csr16, projd, projs, h2b, h2f,
                                            faw, fab, fc, p1d, p1s);
    k_hop1<<<N_NODES / 4, 256, 0, stream>>>(rowptr, csr16, p1d, p1s, fc, h2f, W2, b2, out);
}

// Round 12
// 221.176 us; speedup vs baseline: 1.0836x; 1.0836x over previous
//
#include <hip/hip_runtime.h>
#include <hip/hip_bf16.h>
#include <stdint.h>

constexpr int N_NODES = 50000;
constexpr int N_EDGES = 1600000;
constexpr int IN_DIM  = 500;
constexpr int KPAD    = 512;   // zero-padded K: 16 MFMA steps of 32
constexpr int HID     = 64;
constexpr int OUTC    = 68;    // 64 h2 cols + 4 composed projection cols
constexpr int NCPAD   = 80;    // padded cols: 5 fragments x 16
constexpr int NFRAG   = 5;
constexpr int KSTEPS  = 16;

constexpr int BNODES  = 256;   // nodes per bucket
constexpr int NBUCK   = (N_NODES + BNODES - 1) / BNODES;  // 196
constexpr int EPB     = 8192;  // edges per block (hist/partition)
constexpr int NEBLK   = (N_EDGES + EPB - 1) / EPB;        // 196

#define DEVI __device__ __forceinline__

typedef __attribute__((ext_vector_type(8))) short bf16x8;
typedef __attribute__((ext_vector_type(4))) float f32x4;

DEVI float wred64(float v) {
#pragma unroll
    for (int m = 32; m; m >>= 1) v += __shfl_xor(v, m, 64);
    return v;
}

DEVI float bf_hi(uint32_t u) { return __uint_as_float(u & 0xffff0000u); }
DEVI float bf_lo(uint32_t u) { return __uint_as_float(u << 16); }

DEVI uint16_t f2bf(float f) {
    union { __hip_bfloat16 h; uint16_t u; } c;
    c.h = __float2bfloat16(f);
    return c.u;
}

// ---------------- CSR build: bucketed counting sort ----------------
__global__ __launch_bounds__(256) void k_bhist(const int* __restrict__ dst,
                                               int* __restrict__ bcnt) {
    __shared__ int h[NBUCK];
    int t = threadIdx.x;
    for (int i = t; i < NBUCK; i += 256) h[i] = 0;
    __syncthreads();
    int blockBase = blockIdx.x * EPB;
#pragma unroll
    for (int j = 0; j < 8; ++j) {
        int e = blockBase + j * 1024 + t * 4;
        if (e + 3 < N_EDGES) {
            int4 d4 = *(const int4*)(dst + e);
            atomicAdd(&h[d4.x >> 8], 1);
            atomicAdd(&h[d4.y >> 8], 1);
            atomicAdd(&h[d4.z >> 8], 1);
            atomicAdd(&h[d4.w >> 8], 1);
        }
    }
    __syncthreads();
    for (int i = t; i < NBUCK; i += 256)
        if (h[i]) atomicAdd(&bcnt[i], h[i]);
}

__global__ __launch_bounds__(256) void k_bscan(const int* __restrict__ bcnt,
                                               int* __restrict__ bbase,
                                               int* __restrict__ bcur) {
    __shared__ int s[256];
    int t = threadIdx.x;
    int v = (t < NBUCK) ? bcnt[t] : 0;
    s[t] = v;
    __syncthreads();
    for (int d = 1; d < 256; d <<= 1) {
        int w = (t >= d) ? s[t - d] : 0;
        __syncthreads();
        s[t] += w;
        __syncthreads();
    }
    if (t < NBUCK) {
        bbase[t] = s[t] - v;
        bcur[t]  = s[t] - v;
    }
    if (t == NBUCK - 1) bbase[NBUCK] = s[t];
}

__global__ __launch_bounds__(256) void k_part(const int* __restrict__ src,
                                              const int* __restrict__ dst,
                                              int* __restrict__ bcur,
                                              uint32_t* __restrict__ ebuf) {
    __shared__ int h[NBUCK];
    __shared__ int gb[NBUCK];
    int t = threadIdx.x;
    for (int i = t; i < NBUCK; i += 256) h[i] = 0;
    __syncthreads();
    uint32_t pk[32];
    int blockBase = blockIdx.x * EPB;
#pragma unroll
    for (int j = 0; j < 8; ++j) {
        int e = blockBase + j * 1024 + t * 4;
        if (e + 3 < N_EDGES) {
            int4 s4 = *(const int4*)(src + e);
            int4 d4 = *(const int4*)(dst + e);
            pk[4 * j + 0] = ((uint32_t)d4.x << 16) | (uint32_t)s4.x;
            pk[4 * j + 1] = ((uint32_t)d4.y << 16) | (uint32_t)s4.y;
            pk[4 * j + 2] = ((uint32_t)d4.z << 16) | (uint32_t)s4.z;
            pk[4 * j + 3] = ((uint32_t)d4.w << 16) | (uint32_t)s4.w;
        } else {
            pk[4 * j + 0] = 0xffffffffu;
            pk[4 * j + 1] = 0xffffffffu;
            pk[4 * j + 2] = 0xffffffffu;
            pk[4 * j + 3] = 0xffffffffu;
        }
    }
#pragma unroll
    for (int j = 0; j < 32; ++j) {
        uint32_t b = pk[j] >> 24;
        if (b < NBUCK) atomicAdd(&h[b], 1);
    }
    __syncthreads();
    for (int i = t; i < NBUCK; i += 256)
        gb[i] = h[i] ? atomicAdd(&bcur[i], h[i]) : 0;
    __syncthreads();
#pragma unroll
    for (int j = 0; j < 32; ++j) {
        uint32_t b = pk[j] >> 24;
        if (b < NBUCK) {
            int pos = atomicAdd(&gb[b], 1);
            ebuf[pos] = pk[j];
        }
    }
}

__global__ __launch_bounds__(256) void k_fine(const int* __restrict__ bbase,
                                              const uint32_t* __restrict__ ebuf,
                                              int* __restrict__ rowptr,
                                              float* __restrict__ dinv,
                                              uint16_t* __restrict__ csr16) {
    __shared__ int lcnt[BNODES];
    __shared__ int lcur[BNODES];
    int b = blockIdx.x, t = threadIdx.x;
    int ebase = bbase[b], eend = bbase[b + 1];
    int ecnt = eend - ebase;
    lcnt[t] = 0;
    __syncthreads();
    for (int i = t; i < ecnt; i += 256)
        atomicAdd(&lcnt[(ebuf[ebase + i] >> 16) & 255], 1);
    __syncthreads();
    int myc = lcnt[t];
    lcur[t] = myc;
    __syncthreads();
    for (int d = 1; d < 256; d <<= 1) {
        int w = (t >= d) ? lcur[t - d] : 0;
        __syncthreads();
        lcur[t] += w;
        __syncthreads();
    }
    int excl = lcur[t] - myc;
    int node = b * BNODES + t;
    if (node < N_NODES) {
        rowptr[node] = ebase + excl;
        dinv[node] = rsqrtf((float)(myc > 1 ? myc : 1));
    }
    if (b == NBUCK - 1 && t == 0) rowptr[N_NODES] = eend;
    lcur[t] = ebase + excl;
    __syncthreads();
    for (int i = t; i < ecnt; i += 256) {
        uint32_t pk = ebuf[ebase + i];
        int pos = atomicAdd(&lcur[(pk >> 16) & 255], 1);
        csr16[pos] = (uint16_t)(pk & 0xffffu);
    }
}

// ---- weight prep: composed weights -> bf16 in MFMA-B fragment order ----
__global__ void k_prep(const float* __restrict__ Wl, const float* __restrict__ bl,
                       const float* __restrict__ glw, const float* __restrict__ glb,
                       const float* __restrict__ W1,
                       uint16_t* __restrict__ Wfrag, float* __restrict__ consts) {
    int idx = blockIdx.x * 256 + threadIdx.x;
    if (idx < KPAD * NCPAD) {
        int k = idx / NCPAD, c = idx - k * NCPAD;
        float v = 0.f;
        if (k < IN_DIM && c < OUTC) {
            if (c < HID) {
                v = W1[k * HID + c];
            } else {
                int pp = c - HID, g = pp >> 1, half = pp & 1;
                const float* wv = glw + g * 128 + half * 64;
                float s = 0.f;
                for (int j = 0; j < 64; ++j) s += Wl[k * 64 + j] * wv[j];
                v = s;
            }
        }
        int s  = k >> 5;
        int kk = k & 31;
        int g  = kk >> 3;
        int i  = kk & 7;
        int f  = c >> 4;
        int cl = c & 15;
        int lane = g * 16 + cl;
        Wfrag[(((size_t)s * NFRAG + f) * 64 + lane) * 8 + i] = f2bf(v);
    }
    if (idx < 4) {
        int g = idx >> 1, half = idx & 1;
        const float* wv = glw + g * 128 + half * 64;
        float s = 0.f;
        for (int j = 0; j < 64; ++j) s += bl[j] * wv[j];
        if (half) s += glb[g];
        consts[idx] = s;
    }
}

// ---------------- fused front GEMM via MFMA bf16 ----------------
__global__ __launch_bounds__(256)
void k_gemm_front(const float* __restrict__ x, const uint16_t* __restrict__ Wfrag,
                  const float* __restrict__ consts, const float* __restrict__ b1,
                  const float* __restrict__ dinv,
                  float* __restrict__ h2f, uint16_t* __restrict__ h2b,
                  float4* __restrict__ projd, float4* __restrict__ projs) {
    __shared__ float shp[64][4];
    int tid  = threadIdx.x;
    int wv   = tid >> 6;
    int lane = tid & 63;
    int rbase = blockIdx.x * 64 + wv * 16;
    int row   = rbase + (lane & 15);
    bool rowok = row < N_NODES;
    const float* xr = x + (size_t)row * IN_DIM;
    int koff = (lane >> 4) * 8;

    const bf16x8* wfv = (const bf16x8*)Wfrag;

    f32x4 acc[NFRAG];
#pragma unroll
    for (int f = 0; f < NFRAG; ++f) acc[f] = (f32x4){0.f, 0.f, 0.f, 0.f};

    auto LD4 = [&](int gk) -> float4 {
        float4 v = make_float4(0.f, 0.f, 0.f, 0.f);
        if (rowok) {
            if (gk + 3 < IN_DIM) {
                v = *(const float4*)(xr + gk);
            } else {
                if (gk + 0 < IN_DIM) v.x = xr[gk + 0];
                if (gk + 1 < IN_DIM) v.y = xr[gk + 1];
                if (gk + 2 < IN_DIM) v.z = xr[gk + 2];
                if (gk + 3 < IN_DIM) v.w = xr[gk + 3];
            }
        }
        return v;
    };

    float4 c0 = LD4(koff), c1 = LD4(koff + 4);
    for (int s = 0; s < KSTEPS; ++s) {
        float4 n0, n1;
        if (s < KSTEPS - 1) {
            int gk = (s + 1) * 32 + koff;
            n0 = LD4(gk);
            n1 = LD4(gk + 4);
        }
        bf16x8 af;
        af[0] = (short)f2bf(c0.x); af[1] = (short)f2bf(c0.y);
        af[2] = (short)f2bf(c0.z); af[3] = (short)f2bf(c0.w);
        af[4] = (short)f2bf(c1.x); af[5] = (short)f2bf(c1.y);
        af[6] = (short)f2bf(c1.z); af[7] = (short)f2bf(c1.w);
        const bf16x8* wrow = wfv + (size_t)s * NFRAG * 64 + lane;
#pragma unroll
        for (int f = 0; f < NFRAG; ++f) {
            bf16x8 bf = wrow[f * 64];
            acc[f] = __builtin_amdgcn_mfma_f32_16x16x32_bf16(af, bf, acc[f], 0, 0, 0);
        }
        c0 = n0; c1 = n1;
    }

    int cl  = lane & 15;
    int rg2 = lane >> 4;
#pragma unroll
    for (int f = 0; f < 4; ++f) {
        int c = f * 16 + cl;
        float bc = b1[c];
#pragma unroll
        for (int r = 0; r < 4; ++r) {
            int grow = rbase + rg2 * 4 + r;
            if (grow < N_NODES) {
                float hv = fmaxf(acc[f][r] + bc, 0.f);
                h2f[(size_t)grow * HID + c] = hv;
                h2b[(size_t)grow * HID + c] = f2bf(hv);
            }
        }
    }
    if (cl < 4) {
#pragma unroll
        for (int r = 0; r < 4; ++r) {
            int rl = wv * 16 + rg2 * 4 + r;
            shp[rl][cl] = acc[4][r] + consts[cl];
        }
    }
    __syncthreads();
    if (tid < 64) {
        int grow = blockIdx.x * 64 + tid;
        if (grow < N_NODES) {
            float dv = dinv[grow];
            projd[grow] = make_float4(shp[tid][0], shp[tid][2], dv, 0.f);
            projs[grow] = make_float4(shp[tid][1], shp[tid][3], dv, 0.f);
        }
    }
}

// ---------------- hop 0: on-the-fly factors, bf16 gather, 8x-unrolled broadcast loop ----
__global__ __launch_bounds__(256)
void k_hop0(const int* __restrict__ rowptr, const uint16_t* __restrict__ csr16,
            const float4* __restrict__ projd, const float4* __restrict__ projs,
            const uint16_t* __restrict__ h2b, const float* __restrict__ h2f,
            const float* __restrict__ faw, const float* __restrict__ fab,
            uint32_t* __restrict__ fc, float4* __restrict__ p1d, float4* __restrict__ p1s) {
    int wave = __builtin_amdgcn_readfirstlane(threadIdx.x >> 6);
    int lane = threadIdx.x & 63;
    int v = blockIdx.x * 4 + wave;
    int s = __builtin_amdgcn_readfirstlane(rowptr[v]);
    int e = __builtin_amdgcn_readfirstlane(rowptr[v + 1]);
    float4 pv = projd[v];
    float pd0 = pv.x, pd1 = pv.y, dv = pv.z;
    float acc0 = 0.f, acc1 = 0.f;
    for (int b2 = s; b2 < e; b2 += 64) {
        int pos = b2 + lane;
        bool val = pos < e;
        int uj = val ? (int)csr16[pos] : 0;
        float4 su = val ? projs[uj] : make_float4(0.f, 0.f, 0.f, 0.f);
        float dd = dv * su.z;
        int pkl = (int)((uint32_t)f2bf(tanhf(pd0 + su.x) * dd)
                      | ((uint32_t)f2bf(tanhf(pd1 + su.y) * dd) << 16));
        int cnt = min(64, e - b2);
        int j = 0;
        for (; j + 8 <= cnt; j += 8) {
            int u0 = __shfl(uj, j + 0, 64); uint32_t k0 = (uint32_t)__shfl(pkl, j + 0, 64);
            int u1 = __shfl(uj, j + 1, 64); uint32_t k1 = (uint32_t)__shfl(pkl, j + 1, 64);
            int u2 = __shfl(uj, j + 2, 64); uint32_t k2 = (uint32_t)__shfl(pkl, j + 2, 64);
            int u3 = __shfl(uj, j + 3, 64); uint32_t k3 = (uint32_t)__shfl(pkl, j + 3, 64);
            int u4 = __shfl(uj, j + 4, 64); uint32_t k4 = (uint32_t)__shfl(pkl, j + 4, 64);
            int u5 = __shfl(uj, j + 5, 64); uint32_t k5 = (uint32_t)__shfl(pkl, j + 5, 64);
            int u6 = __shfl(uj, j + 6, 64); uint32_t k6 = (uint32_t)__shfl(pkl, j + 6, 64);
            int u7 = __shfl(uj, j + 7, 64); uint32_t k7 = (uint32_t)__shfl(pkl, j + 7, 64);
            uint32_t h0 = h2b[(size_t)u0 * 64 + lane];
            uint32_t h1 = h2b[(size_t)u1 * 64 + lane];
            uint32_t h2 = h2b[(size_t)u2 * 64 + lane];
            uint32_t h3 = h2b[(size_t)u3 * 64 + lane];
            uint32_t h4 = h2b[(size_t)u4 * 64 + lane];
            uint32_t h5 = h2b[(size_t)u5 * 64 + lane];
            uint32_t h6 = h2b[(size_t)u6 * 64 + lane];
            uint32_t h7 = h2b[(size_t)u7 * 64 + lane];
            float f0 = bf_lo(h0), f1 = bf_lo(h1), f2 = bf_lo(h2), f3 = bf_lo(h3);
            float f4 = bf_lo(h4), f5 = bf_lo(h5), f6 = bf_lo(h6), f7 = bf_lo(h7);
            acc0 = fmaf(bf_lo(k0), f0, acc0); acc1 = fmaf(bf_hi(k0), f0, acc1);
            acc0 = fmaf(bf_lo(k1), f1, acc0); acc1 = fmaf(bf_hi(k1), f1, acc1);
            acc0 = fmaf(bf_lo(k2), f2, acc0); acc1 = fmaf(bf_hi(k2), f2, acc1);
            acc0 = fmaf(bf_lo(k3), f3, acc0); acc1 = fmaf(bf_hi(k3), f3, acc1);
            acc0 = fmaf(bf_lo(k4), f4, acc0); acc1 = fmaf(bf_hi(k4), f4, acc1);
            acc0 = fmaf(bf_lo(k5), f5, acc0); acc1 = fmaf(bf_hi(k5), f5, acc1);
            acc0 = fmaf(bf_lo(k6), f6, acc0); acc1 = fmaf(bf_hi(k6), f6, acc1);
            acc0 = fmaf(bf_lo(k7), f7, acc0); acc1 = fmaf(bf_hi(k7), f7, acc1);
        }
        for (; j < cnt; ++j) {
            int u = __shfl(uj, j, 64);
            uint32_t pk = (uint32_t)__shfl(pkl, j, 64);
            float hv = bf_lo((uint32_t)h2b[(size_t)u * 64 + lane]);
            acc0 = fmaf(bf_lo(pk), hv, acc0);
            acc1 = fmaf(bf_hi(pk), hv, acc1);
        }
    }
    float h2v = h2f[(size_t)v * 64 + lane];
    float f0 = fmaf(0.7f, acc0, 0.3f * h2v);
    float f1 = fmaf(0.7f, acc1, 0.3f * h2v);
    fc[(size_t)v * 64 + lane] = (uint32_t)f2bf(f0) | ((uint32_t)f2bf(f1) << 16);
    float wpd0 = faw[1 * 128 + lane];
    float wps0 = faw[1 * 128 + 64 + lane];
    float wpd1 = faw[3 * 128 + lane];
    float wps1 = faw[3 * 128 + 64 + lane];
    float r0 = wred64(f0 * wpd0);
    float r1 = wred64(f0 * wps0);
    float r2 = wred64(f1 * wpd1);
    float r3 = wred64(f1 * wps1);
    if (lane == 0) {
        p1d[v] = make_float4(r0, r2, dv, 0.f);
        p1s[v] = make_float4(r1 + fab[1], r3 + fab[3], dv, 0.f);
    }
}

// ---------------- hop 1 + final output GEMM [128]->7, 8x-unrolled ----
__global__ __launch_bounds__(256)
void k_hop1(const int* __restrict__ rowptr, const uint16_t* __restrict__ csr16,
            const float4* __restrict__ p1d, const float4* __restrict__ p1s,
            const uint32_t* __restrict__ fc, const float* __restrict__ h2f,
            const float* __restrict__ W2, const float* __restrict__ b2,
            float* __restrict__ out) {
    int wave = __builtin_amdgcn_readfirstlane(threadIdx.x >> 6);
    int lane = threadIdx.x & 63;
    int v = blockIdx.x * 4 + wave;
    int s = __builtin_amdgcn_readfirstlane(rowptr[v]);
    int e = __builtin_amdgcn_readfirstlane(rowptr[v + 1]);
    float4 pv = p1d[v];
    float pd0 = pv.x, pd1 = pv.y, dv = pv.z;
    float acc0 = 0.f, acc1 = 0.f;
    for (int b2 = s; b2 < e; b2 += 64) {
        int pos = b2 + lane;
        bool val = pos < e;
        int uj = val ? (int)csr16[pos] : 0;
        float4 su = val ? p1s[uj] : make_float4(0.f, 0.f, 0.f, 0.f);
        float dd = dv * su.z;
        int pkl = (int)((uint32_t)f2bf(tanhf(pd0 + su.x) * dd)
                      | ((uint32_t)f2bf(tanhf(pd1 + su.y) * dd) << 16));
        int cnt = min(64, e - b2);
        int j = 0;
        for (; j + 8 <= cnt; j += 8) {
            int u0 = __shfl(uj, j + 0, 64); uint32_t k0 = (uint32_t)__shfl(pkl, j + 0, 64);
            int u1 = __shfl(uj, j + 1, 64); uint32_t k1 = (uint32_t)__shfl(pkl, j + 1, 64);
            int u2 = __shfl(uj, j + 2, 64); uint32_t k2 = (uint32_t)__shfl(pkl, j + 2, 64);
            int u3 = __shfl(uj, j + 3, 64); uint32_t k3 = (uint32_t)__shfl(pkl, j + 3, 64);
            int u4 = __shfl(uj, j + 4, 64); uint32_t k4 = (uint32_t)__shfl(pkl, j + 4, 64);
            int u5 = __shfl(uj, j + 5, 64); uint32_t k5 = (uint32_t)__shfl(pkl, j + 5, 64);
            int u6 = __shfl(uj, j + 6, 64); uint32_t k6 = (uint32_t)__shfl(pkl, j + 6, 64);
            int u7 = __shfl(uj, j + 7, 64); uint32_t k7 = (uint32_t)__shfl(pkl, j + 7, 64);
            uint32_t g0 = fc[(size_t)u0 * 64 + lane];
            uint32_t g1 = fc[(size_t)u1 * 64 + lane];
            uint32_t g2 = fc[(size_t)u2 * 64 + lane];
            uint32_t g3 = fc[(size_t)u3 * 64 + lane];
            uint32_t g4 = fc[(size_t)u4 * 64 + lane];
            uint32_t g5 = fc[(size_t)u5 * 64 + lane];
            uint32_t g6 = fc[(size_t)u6 * 64 + lane];
            uint32_t g7 = fc[(size_t)u7 * 64 + lane];
            acc0 = fmaf(bf_lo(k0), bf_lo(g0), acc0); acc1 = fmaf(bf_hi(k0), bf_hi(g0), acc1);
            acc0 = fmaf(bf_lo(k1), bf_lo(g1), acc0); acc1 = fmaf(bf_hi(k1), bf_hi(g1), acc1);
            acc0 = fmaf(bf_lo(k2), bf_lo(g2), acc0); acc1 = fmaf(bf_hi(k2), bf_hi(g2), acc1);
            acc0 = fmaf(bf_lo(k3), bf_lo(g3), acc0); acc1 = fmaf(bf_hi(k3), bf_hi(g3), acc1);
            acc0 = fmaf(bf_lo(k4), bf_lo(g4), acc0); acc1 = fmaf(bf_hi(k4), bf_hi(g4), acc1);
            acc0 = fmaf(bf_lo(k5), bf_lo(g5), acc0); acc1 = fmaf(bf_hi(k5), bf_hi(g5), acc1);
            acc0 = fmaf(bf_lo(k6), bf_lo(g6), acc0); acc1 = fmaf(bf_hi(k6), bf_hi(g6), acc1);
            acc0 = fmaf(bf_lo(k7), bf_lo(g7), acc0); acc1 = fmaf(bf_hi(k7), bf_hi(g7), acc1);
        }
        for (; j < cnt; ++j) {
            int u = __shfl(uj, j, 64);
            uint32_t pk = (uint32_t)__shfl(pkl, j, 64);
            uint32_t g = fc[(size_t)u * 64 + lane];
            acc0 = fmaf(bf_lo(pk), bf_lo(g), acc0);
            acc1 = fmaf(bf_hi(pk), bf_hi(g), acc1);
        }
    }
    float h2v = h2f[(size_t)v * 64 + lane];
    float f0 = fmaf(0.7f, acc0, 0.3f * h2v);
    float f1 = fmaf(0.7f, acc1, 0.3f * h2v);
#pragma unroll
    for (int o = 0; o < 7; ++o) {
        float contrib = f0 * W2[lane * 7 + o] + f1 * W2[(64 + lane) * 7 + o];
        float sum = wred64(contrib);
        if (lane == 0) out[v * 7 + o] = sum + b2[o];
    }
}

extern "C" void kernel_launch(void* const* d_in, const int* in_sizes, int n_in,
                              void* d_out, int out_size, void* d_ws, size_t ws_size,
                              hipStream_t stream) {
    const float* x   = (const float*)d_in[0];
    const int*   src = (const int*)d_in[1];
    const int*   dst = (const int*)d_in[2];
    const float* Wl  = (const float*)d_in[3];
    const float* bl  = (const float*)d_in[4];
    const float* glw = (const float*)d_in[5];
    const float* glb = (const float*)d_in[6];
    const float* W1  = (const float*)d_in[7];
    const float* b1  = (const float*)d_in[8];
    const float* faw = (const float*)d_in[9];
    const float* fab = (const float*)d_in[10];
    const float* W2  = (const float*)d_in[11];
    const float* b2  = (const float*)d_in[12];
    float* out = (float*)d_out;

    uint8_t* p = (uint8_t*)d_ws;
    auto carve = [&](size_t bytes) {
        uint8_t* q = p;
        p += (bytes + 255) & ~(size_t)255;
        return q;
    };
    uint16_t* Wfrag   = (uint16_t*)carve((size_t)KPAD * NCPAD * 2);
    float*    consts  = (float*)carve(16);
    int*      bcnt    = (int*)carve(NBUCK * 4);
    int*      bbase   = (int*)carve((NBUCK + 1) * 4);
    int*      bcur    = (int*)carve(NBUCK * 4);
    int*      rowptr  = (int*)carve((N_NODES + 1) * 4);
    float*    dinv    = (float*)carve(N_NODES * 4);
    uint32_t* ebuf    = (uint32_t*)carve((size_t)N_EDGES * 4);
    uint16_t* csr16   = (uint16_t*)carve((size_t)N_EDGES * 2);
    float*    h2f     = (float*)carve((size_t)N_NODES * 64 * 4);
    uint16_t* h2b     = (uint16_t*)carve((size_t)N_NODES * 64 * 2);
    float4*   projd   = (float4*)carve((size_t)N_NODES * 16);
    float4*   projs   = (float4*)carve((size_t)N_NODES * 16);
    uint32_t* fc      = (uint32_t*)carve((size_t)N_NODES * 64 * 4);
    float4*   p1d     = (float4*)carve((size_t)N_NODES * 16);
    float4*   p1s     = (float4*)carve((size_t)N_NODES * 16);

    hipMemsetAsync(bcnt, 0, NBUCK * 4, stream);
    k_bhist<<<NEBLK, 256, 0, stream>>>(dst, bcnt);
    k_bscan<<<1, 256, 0, stream>>>(bcnt, bbase, bcur);
    k_part<<<NEBLK, 256, 0, stream>>>(src, dst, bcur, ebuf);
    k_fine<<<NBUCK, 256, 0, stream>>>(bbase, ebuf, rowptr, dinv, csr16);
    k_prep<<<(KPAD * NCPAD + 255) / 256, 256, 0, stream>>>(Wl, bl, glw, glb, W1, Wfrag, consts);
    k_gemm_front<<<(N_NODES + 63) / 64, 256, 0, stream>>>(x, Wfrag, consts, b1, dinv,
                                                          h2f, h2b, projd, projs);
    k_hop0<<<N_NODES / 4, 256, 0, stream>>>(rowptr, csr16, projd, projs, h2b, h2f,
                                            faw, fab, fc, p1d, p1s);
    k_hop1<<<N_NODES / 4, 256, 0, stream>>>(rowptr, csr16, p1d, p1s, fc, h2f, W2, b2, out);
}